// Round 5
// baseline (395.607 us; speedup 1.0000x reference)
//
#include <hip/hip_runtime.h>
#include <cstdint>

#define D_CH 128
#define T_LEN 1024
#define ROWLEN 384
#define NROWS (128 * 1024)
#define TILE 64
#define NCHUNK (NROWS / TILE)   // 2048
#define VSTR_B 272              // vs row stride bytes (136 f16) — conflict-free b128 reads
#define EPI_W 132               // epi row stride words (pad 4)
#define SLICE_B 4352            // per-wave slice: vh pane 16*272; epi 8-row pane (4224) aliases
                                // 4 waves * 4352 = 17408 B/block -> 8 blocks/CU (32 waves!)

typedef __attribute__((ext_vector_type(8))) _Float16 f16x8;
typedef __attribute__((ext_vector_type(4))) _Float16 f16x4;
typedef __attribute__((ext_vector_type(4))) float f32x4;

// Kernel A: per-(b,d) partial means over T (S-way split across blocks for 2x CU
// parallelism) + kernel matrix -> f16 in MFMA-B fragment order.
// Each partial is pre-scaled by 1/1024; main sums the S partials.
// Loads stay NORMAL (not nt) so y warms L3 for main.
__global__ __launch_bounds__(1024) void prep_kernel(const float* __restrict__ x,
                                                    const float* __restrict__ Kmat,
                                                    float* __restrict__ meang,
                                                    _Float16* __restrict__ Ktg,
                                                    int S, int JITER) {
  int bid = blockIdx.x;            // 256*S blocks: (b, half-of-D, tq)
  int bh = bid / S;
  int tq = bid - bh * S;
  int b = bh >> 1, h = bh & 1;
  int tid = threadIdx.x;
  int li = tid & 15, tt = tid >> 4;      // 16 d-groups x 64 t-slices
  int d4 = h * 64 + 4 * li;
  f32x4 s = {0.f, 0.f, 0.f, 0.f};
  const float* xp = x + (size_t)b * T_LEN * ROWLEN + d4;
  int t0 = tq * (T_LEN / S) + tt;
#pragma unroll 4
  for (int j = 0; j < JITER; ++j) {
    int t = t0 + 64 * j;
    f32x4 v = *(const f32x4*)(xp + (size_t)t * ROWLEN);
    s += v;
  }
  __shared__ f32x4 red[64][17];          // 17408 B
  red[tt][li] = s;
  __syncthreads();
  for (int st = 32; st > 0; st >>= 1) {
    if (tt < st) red[tt][li] += red[tt + st][li];
    __syncthreads();
  }
  if (tt == 0) {
    f32x4 m = red[0][li] * (1.0f / 1024.0f);
    *(f32x4*)(meang + (size_t)(b * S + tq) * D_CH + d4) = m;
  }
  // fragment-order Kt: 64 f16 per (b,h) (16384 total, bijective); tq==0 blocks only
  if (tq == 0 && tid < 64) {
    int f = bh * 64 + tid;
    int j = f & 7;
    int lane = (f >> 3) & 63;
    int q = f >> 9;                 // 0..31 = nt*4 + ks
    int ks = q & 3, nt = q >> 2;
    int kk = ks * 32 + (lane >> 4) * 8 + j;
    int nn = nt * 16 + (lane & 15);
    Ktg[f] = (_Float16)Kmat[kk * D_CH + nn];
  }
}

// Kernel B: fused softmax + MFMA matmul + TWO-PASS vectorized epilogue. ZERO barriers.
// Round-5 changes (r4's 5-block/96-VGPR-cap gamble reverted):
//  - epilogue staged 8 rows at a time: epi pane = 8*132*4 = 4224 B fits INSIDE the
//    4352 B vh pane -> LDS 33792 -> 17408 B/block. With the compiler's 64-VGPR
//    schedule (r1 counter evidence) residency becomes 8 blocks/CU = 32 waves/CU
//    (2x r2) for this latency-bound kernel; grid 2048 = exactly 8/CU, zero tail.
//  - masked scatter rows differ by 4*132 ≡ 16 mod 32 -> the two active 16-lane
//    groups hit disjoint bank halves: conflict-free (better than r2's 2-way).
//  - __launch_bounds__(256,6): VGPR cap 84, comfortably above the 64 in use
//    (r4's (256,5) cap of 96 was at the edge of peak-live — the suspected spill).
__global__ __launch_bounds__(256, 6) void main_kernel(const float* __restrict__ x,
                                                      const float* __restrict__ meang,
                                                      const _Float16* __restrict__ Ktg,
                                                      float* __restrict__ out,
                                                      int S) {
  __shared__ alignas(16) char smem[4 * SLICE_B];      // 17408 B -> 8 blocks/CU
  int tid = threadIdx.x;
  int wave = tid >> 6, lane = tid & 63;
  int hf = lane >> 5, li = lane & 31;
  int c0 = 4 * li;
  int m0 = wave * 16;                    // wave-private 16 rows of the 64-row tile
  int l15 = lane & 15, lg = lane >> 4;
  char* vslice = smem + wave * SLICE_B;
  float* epi = (float*)(smem + wave * SLICE_B);       // aliases vslice (WAR/RAW-safe:
                                                      // per-wave in-order DS pipe)
  int chunk = blockIdx.x;                // grid == NCHUNK: one chunk per block
  int row0 = chunk * TILE;
  int bb = chunk >> 4;                   // T/TILE = 16 chunks per batch
  f32x4 mn = {0.f, 0.f, 0.f, 0.f};
  for (int s = 0; s < S; ++s)
    mn += *(const f32x4*)(meang + (size_t)(bb * S + s) * D_CH + c0);

  // ---- phase 1: load y,w; exp; store intensity; softmax; v -> LDS (f16 row-major) ----
  f32x4 yb[8], wb[8];
#pragma unroll
  for (int i = 0; i < 8; ++i) {
    size_t base = (size_t)(row0 + m0 + 2 * i + hf) * ROWLEN + c0;
    yb[i] = __builtin_nontemporal_load((const f32x4*)(x + base));
    wb[i] = __builtin_nontemporal_load((const f32x4*)(x + base + 128));
  }
#pragma unroll
  for (int i = 0; i < 8; ++i) {
    int lr = 2 * i + hf;
    int row = row0 + m0 + lr;
    f32x4 e;
    e[0] = __expf(wb[i][0]); e[1] = __expf(wb[i][1]);
    e[2] = __expf(wb[i][2]); e[3] = __expf(wb[i][3]);
    __builtin_nontemporal_store(e, (f32x4*)(out + (size_t)row * ROWLEN + 128 + c0));  // intensity
    float s = e[0] + e[1] + e[2] + e[3];                      // |w| small: no max-sub needed
    s += __shfl_xor(s, 1, 32);
    s += __shfl_xor(s, 2, 32);
    s += __shfl_xor(s, 4, 32);
    s += __shfl_xor(s, 8, 32);
    s += __shfl_xor(s, 16, 32);
    float rinv = 1.0f / s;
    f16x4 vh;
    vh[0] = (_Float16)(e[0] * rinv * (yb[i][0] - mn[0]));
    vh[1] = (_Float16)(e[1] * rinv * (yb[i][1] - mn[1]));
    vh[2] = (_Float16)(e[2] * rinv * (yb[i][2] - mn[2]));
    vh[3] = (_Float16)(e[3] * rinv * (yb[i][3] - mn[3]));
    *(f16x4*)(vslice + lr * VSTR_B + li * 8) = vh;
  }

  // ---- y_obs loads (latency hidden by 32-wave TLP + MFMA stretch) ----
  f32x4 yo[8];
#pragma unroll
  for (int i = 0; i < 8; ++i) {
    size_t base = (size_t)(row0 + m0 + 2 * i + hf) * ROWLEN + c0;
    yo[i] = __builtin_nontemporal_load((const f32x4*)(x + base + 256));
  }

  // ---- phase 2: A-frags from LDS, B-frags from global frag-order table (L2-hot 32KB) ----
  f16x8 a[4];
#pragma unroll
  for (int ks = 0; ks < 4; ++ks)
    a[ks] = *(const f16x8*)(vslice + l15 * VSTR_B + ks * 64 + lg * 16);
  f32x4 acc[8];
#pragma unroll
  for (int nt = 0; nt < 8; ++nt) {
    acc[nt] = (f32x4){0.f, 0.f, 0.f, 0.f};
#pragma unroll
    for (int ks = 0; ks < 4; ++ks) {
      f16x8 bf = *(const f16x8*)&Ktg[((nt * 4 + ks) * 64 + lane) * 8];
      acc[nt] = __builtin_amdgcn_mfma_f32_16x16x32_f16(a[ks], bf, acc[nt], 0, 0, 0);
    }
  }

  // ---- two-pass epilogue: 8 rows per pass through the (aliased) 4224 B pane ----
#pragma unroll
  for (int p = 0; p < 2; ++p) {
    // scatter: lanes owning rows [p*8, p*8+8) write; local row = (lg&1)*4 + r
    if ((lg >> 1) == p) {
#pragma unroll
      for (int nt = 0; nt < 8; ++nt)
#pragma unroll
        for (int r = 0; r < 4; ++r)
          epi[((lg & 1) * 4 + r) * EPI_W + nt * 16 + l15] = acc[nt][r];
    }
    // gather + fused adds + stores (per-wave in-order DS pipe orders write->read)
#pragma unroll
    for (int i = 0; i < 4; ++i) {
      int lrl = 2 * i + hf;                    // local row 0..7
      int gi = p * 4 + i;                      // yo index: global row = 2*gi + hf + ...
      size_t ob = (size_t)(row0 + m0 + p * 8 + lrl) * ROWLEN;
      f32x4 sm4 = *(const f32x4*)&epi[lrl * EPI_W + c0];
      sm4 += mn;
      __builtin_nontemporal_store(sm4, (f32x4*)(out + ob + c0));                  // smooth
      f32x4 yt = yo[gi] - sm4;
      __builtin_nontemporal_store(yt, (f32x4*)(out + ob + 256 + c0));             // y_trans
    }
  }
}

extern "C" void kernel_launch(void* const* d_in, const int* in_sizes, int n_in,
                              void* d_out, int out_size, void* d_ws, size_t ws_size,
                              hipStream_t stream) {
  const float* x = (const float*)d_in[0];
  const float* Kmat = (const float*)d_in[1];
  float* out = (float*)d_out;
  // S-way split prep needs S*64KB (partial means) + 32KB (Ktg); fall back if ws is tight
  int S = (ws_size >= (size_t)(2 * 65536 + 32768)) ? 2 : 1;
  float* meang = (float*)d_ws;                          // 128*S*128 f32
  _Float16* Ktg = (_Float16*)((char*)d_ws + (size_t)S * 65536);  // 16384 f16 (frag order)
  prep_kernel<<<256 * S, 1024, 0, stream>>>(x, Kmat, meang, Ktg, S, 16 / S);
  main_kernel<<<NCHUNK, 256, 0, stream>>>(x, meang, Ktg, out, S);
}

// Round 6
// 343.178 us; speedup vs baseline: 1.1528x; 1.1528x over previous
//
#include <hip/hip_runtime.h>
#include <cstdint>

#define D_CH 128
#define T_LEN 1024
#define ROWLEN 384
#define NROWS (128 * 1024)
#define TILE 64
#define NCHUNK (NROWS / TILE)   // 2048
#define VSTR_B 272              // vs row stride bytes (136 f16) — conflict-free b128 reads
#define EPI16_W 132             // epi row stride in f16 elems (pad 4): 264 B/row
#define SLICE_B 4352            // per-wave slice: vh pane 16*272 B; f16 epi pane
                                // (16*264 = 4224 B) aliases it. 4 waves * 4352 =
                                // 17408 B/block -> 8 blocks/CU at 64 VGPR (32 waves)

typedef __attribute__((ext_vector_type(8))) _Float16 f16x8;
typedef __attribute__((ext_vector_type(4))) _Float16 f16x4;
typedef __attribute__((ext_vector_type(4))) float f32x4;

// Kernel A: per-(b,d) partial means over T (S-way split across blocks for 2x CU
// parallelism) + kernel matrix -> f16 in MFMA-B fragment order.
// Each partial is pre-scaled by 1/1024; main sums the S partials.
// Loads stay NORMAL (not nt) so y warms L3 for main.
__global__ __launch_bounds__(1024) void prep_kernel(const float* __restrict__ x,
                                                    const float* __restrict__ Kmat,
                                                    float* __restrict__ meang,
                                                    _Float16* __restrict__ Ktg,
                                                    int S, int JITER) {
  int bid = blockIdx.x;            // 256*S blocks: (b, half-of-D, tq)
  int bh = bid / S;
  int tq = bid - bh * S;
  int b = bh >> 1, h = bh & 1;
  int tid = threadIdx.x;
  int li = tid & 15, tt = tid >> 4;      // 16 d-groups x 64 t-slices
  int d4 = h * 64 + 4 * li;
  f32x4 s = {0.f, 0.f, 0.f, 0.f};
  const float* xp = x + (size_t)b * T_LEN * ROWLEN + d4;
  int t0 = tq * (T_LEN / S) + tt;
#pragma unroll 4
  for (int j = 0; j < JITER; ++j) {
    int t = t0 + 64 * j;
    f32x4 v = *(const f32x4*)(xp + (size_t)t * ROWLEN);
    s += v;
  }
  __shared__ f32x4 red[64][17];          // 17408 B
  red[tt][li] = s;
  __syncthreads();
  for (int st = 32; st > 0; st >>= 1) {
    if (tt < st) red[tt][li] += red[tt + st][li];
    __syncthreads();
  }
  if (tt == 0) {
    f32x4 m = red[0][li] * (1.0f / 1024.0f);
    *(f32x4*)(meang + (size_t)(b * S + tq) * D_CH + d4) = m;
  }
  // fragment-order Kt: 64 f16 per (b,h) (16384 total, bijective); tq==0 blocks only
  if (tq == 0 && tid < 64) {
    int f = bh * 64 + tid;
    int j = f & 7;
    int lane = (f >> 3) & 63;
    int q = f >> 9;                 // 0..31 = nt*4 + ks
    int ks = q & 3, nt = q >> 2;
    int kk = ks * 32 + (lane >> 4) * 8 + j;
    int nn = nt * 16 + (lane & 15);
    Ktg[f] = (_Float16)Kmat[kk * D_CH + nn];
  }
}

// Kernel B: fused softmax + MFMA matmul + f16-staged epilogue. ZERO barriers.
// Round-6 (fixing r5's two failure modes):
//  - r5's VGPR_Count=40 + WRITE_SIZE+130MB = launch-bounds-induced scratch spill;
//    back to proven (256,4) (r1/r2 compiled this shape to 64 VGPR, zero spill).
//  - r5's divergent two-pass epi (absmax 1.01) replaced by SINGLE-pass f16 pane:
//    16 rows x 132 f16 = 4224 B fits in the 4352 B vh pane (aliased write-after-
//    MFMA, the exact pattern r4 validated at absmax 0.0625). f16 smooth staging
//    adds ~5e-4 abs — negligible. LDS stays 17408 B -> 8 blocks/CU, 32 waves.
//  - yo loads back in the epilogue (issued between scatter and gather): 32-wave
//    TLP hides them; MFMA-region live set ~58 regs -> natural 64-VGPR schedule.
__global__ __launch_bounds__(256, 4) void main_kernel(const float* __restrict__ x,
                                                      const float* __restrict__ meang,
                                                      const _Float16* __restrict__ Ktg,
                                                      float* __restrict__ out,
                                                      int S) {
  __shared__ alignas(16) char smem[4 * SLICE_B];      // 17408 B
  int tid = threadIdx.x;
  int wave = tid >> 6, lane = tid & 63;
  int hf = lane >> 5, li = lane & 31;
  int c0 = 4 * li;
  int m0 = wave * 16;                    // wave-private 16 rows of the 64-row tile
  int l15 = lane & 15, lg = lane >> 4;
  char* vslice = smem + wave * SLICE_B;
  _Float16* epi16 = (_Float16*)(smem + wave * SLICE_B); // aliases vslice (write-after-
                                                        // MFMA: a[] already consumed)
  int chunk = blockIdx.x;                // grid == NCHUNK: one chunk per block
  int row0 = chunk * TILE;
  int bb = chunk >> 4;                   // T/TILE = 16 chunks per batch
  f32x4 mn = {0.f, 0.f, 0.f, 0.f};
  for (int s = 0; s < S; ++s)
    mn += *(const f32x4*)(meang + (size_t)(bb * S + s) * D_CH + c0);

  // ---- phase 1: load y,w; exp; store intensity; softmax; v -> LDS (f16 row-major) ----
  f32x4 yb[8], wb[8];
#pragma unroll
  for (int i = 0; i < 8; ++i) {
    size_t base = (size_t)(row0 + m0 + 2 * i + hf) * ROWLEN + c0;
    yb[i] = __builtin_nontemporal_load((const f32x4*)(x + base));
    wb[i] = __builtin_nontemporal_load((const f32x4*)(x + base + 128));
  }
#pragma unroll
  for (int i = 0; i < 8; ++i) {
    int lr = 2 * i + hf;
    int row = row0 + m0 + lr;
    f32x4 e;
    e[0] = __expf(wb[i][0]); e[1] = __expf(wb[i][1]);
    e[2] = __expf(wb[i][2]); e[3] = __expf(wb[i][3]);
    __builtin_nontemporal_store(e, (f32x4*)(out + (size_t)row * ROWLEN + 128 + c0));  // intensity
    float s = e[0] + e[1] + e[2] + e[3];                      // |w| small: no max-sub needed
    s += __shfl_xor(s, 1, 32);
    s += __shfl_xor(s, 2, 32);
    s += __shfl_xor(s, 4, 32);
    s += __shfl_xor(s, 8, 32);
    s += __shfl_xor(s, 16, 32);
    float rinv = 1.0f / s;
    f16x4 vh;
    vh[0] = (_Float16)(e[0] * rinv * (yb[i][0] - mn[0]));
    vh[1] = (_Float16)(e[1] * rinv * (yb[i][1] - mn[1]));
    vh[2] = (_Float16)(e[2] * rinv * (yb[i][2] - mn[2]));
    vh[3] = (_Float16)(e[3] * rinv * (yb[i][3] - mn[3]));
    *(f16x4*)(vslice + lr * VSTR_B + li * 8) = vh;
  }

  // ---- phase 2: A-frags from LDS, B-frags from global frag-order table (L2-hot 32KB) ----
  f16x8 a[4];
#pragma unroll
  for (int ks = 0; ks < 4; ++ks)
    a[ks] = *(const f16x8*)(vslice + l15 * VSTR_B + ks * 64 + lg * 16);
  f32x4 acc[8];
#pragma unroll
  for (int nt = 0; nt < 8; ++nt) {
    acc[nt] = (f32x4){0.f, 0.f, 0.f, 0.f};
#pragma unroll
    for (int ks = 0; ks < 4; ++ks) {
      f16x8 bf = *(const f16x8*)&Ktg[((nt * 4 + ks) * 64 + lane) * 8];
      acc[nt] = __builtin_amdgcn_mfma_f32_16x16x32_f16(a[ks], bf, acc[nt], 0, 0, 0);
    }
  }

  // ---- epilogue: C-layout -> f16 LDS pane (conflict-free scatter), single pass ----
  // write: row = lg*4+r (C/D layout), col = nt*16+l15; rows stride 66 words ≡ 2 mod 32,
  // lg groups offset 8 banks apart -> 2 lanes/bank (free).
#pragma unroll
  for (int nt = 0; nt < 8; ++nt)
#pragma unroll
    for (int r = 0; r < 4; ++r)
      epi16[(lg * 4 + r) * EPI16_W + nt * 16 + l15] = (_Float16)acc[nt][r];

  // yo loads issued here: vmcnt latency overlaps the f16 gather + converts below,
  // and 32-wave TLP covers the rest.
  f32x4 yo[8];
#pragma unroll
  for (int i = 0; i < 8; ++i) {
    size_t base = (size_t)(row0 + m0 + 2 * i + hf) * ROWLEN + c0;
    yo[i] = __builtin_nontemporal_load((const f32x4*)(x + base + 256));
  }

#pragma unroll
  for (int i = 0; i < 8; ++i) {
    int lr = 2 * i + hf;
    size_t ob = (size_t)(row0 + m0 + lr) * ROWLEN;
    f16x4 sh = *(const f16x4*)&epi16[lr * EPI16_W + c0];
    f32x4 sm4;
    sm4[0] = (float)sh[0] + mn[0];
    sm4[1] = (float)sh[1] + mn[1];
    sm4[2] = (float)sh[2] + mn[2];
    sm4[3] = (float)sh[3] + mn[3];
    __builtin_nontemporal_store(sm4, (f32x4*)(out + ob + c0));                    // smooth
    f32x4 yt = yo[i] - sm4;
    __builtin_nontemporal_store(yt, (f32x4*)(out + ob + 256 + c0));               // y_trans
  }
}

extern "C" void kernel_launch(void* const* d_in, const int* in_sizes, int n_in,
                              void* d_out, int out_size, void* d_ws, size_t ws_size,
                              hipStream_t stream) {
  const float* x = (const float*)d_in[0];
  const float* Kmat = (const float*)d_in[1];
  float* out = (float*)d_out;
  // S-way split prep needs S*64KB (partial means) + 32KB (Ktg); fall back if ws is tight
  int S = (ws_size >= (size_t)(2 * 65536 + 32768)) ? 2 : 1;
  float* meang = (float*)d_ws;                          // 128*S*128 f32
  _Float16* Ktg = (_Float16*)((char*)d_ws + (size_t)S * 65536);  // 16384 f16 (frag order)
  prep_kernel<<<256 * S, 1024, 0, stream>>>(x, Kmat, meang, Ktg, S, 16 / S);
  main_kernel<<<NCHUNK, 256, 0, stream>>>(x, meang, Ktg, out, S);
}